// Round 1
// baseline (407.646 us; speedup 1.0000x reference)
//
#include <hip/hip_runtime.h>
#include <hip/hip_bf16.h>

// Problem constants
#define DM   96
#define DI   192
#define DXZ  384
#define BB   8
#define LL   4096
#define BLT  32768   // B*L
#define NCHUNK 128
#define CLEN   32    // chunk length; NCHUNK*CLEN == LL

// Workspace layout (float offsets)
#define XPRE_OFF   0u          // [B*L,192] x pre-conv
#define Z_OFF      6291456u    // [B*L,192] z (gate)
#define XPOST_OFF  12582912u   // [B*L,192] x post conv+silu
#define DELTA_OFF  18874368u   // [B*L,192] softplus delta
#define BC_OFF     25165824u   // [B*L,16]  B(8) then C(8)
#define P_OFF      25690112u   // [B,192,NCHUNK,8] chunk product of deltaA
#define Q_OFF      27262976u   // [B,192,NCHUNK,8] chunk local final h
#define KC_OFF     28835840u   // [B,192,NCHUNK,8] correction coeff
#define YSUM_OFF   30408704u   // [B,192]
#define USUM_OFF   30410240u   // [B,96]

// ---------------------------------------------------------------------------
// K1: RMSNorm + xz = xn @ W_in.T   ([B*L,96] @ [96,384]); also u column sums.
// One block = 32 positions. Thread (p=tid&31, jb=tid>>5) computes 48 outputs.
// ---------------------------------------------------------------------------
__global__ __launch_bounds__(256) void k_rms_gemm(
    const float* __restrict__ u, const float* __restrict__ norm_w,
    const float* __restrict__ W_in, float* __restrict__ xpre,
    float* __restrict__ zbuf, float* __restrict__ usum)
{
  __shared__ float su[32 * 100];     // u tile, row stride 100 (pad, 16B-aligned)
  __shared__ float sout[32 * 385];   // output tile, +1 pad kills bank conflicts
  __shared__ float sscale[32];
  const int tid  = threadIdx.x;
  const int base = blockIdx.x * 32;
  const int b    = base >> 12;       // / LL

  for (int idx = tid; idx < 32 * 96; idx += 256) {
    int p = idx / 96, k = idx - p * 96;
    su[p * 100 + k] = u[(base + p) * 96 + k];
  }
  __syncthreads();

  if (tid < 96) {                    // raw-u column partial sums (for e.mean)
    float s = 0.f;
    #pragma unroll 8
    for (int p = 0; p < 32; ++p) s += su[p * 100 + tid];
    atomicAdd(&usum[b * 96 + tid], s);
  } else if (tid < 128) {            // rms scale per position
    int p = tid - 96;
    float s = 0.f;
    #pragma unroll 8
    for (int k = 0; k < 96; ++k) { float v = su[p * 100 + k]; s += v * v; }
    sscale[p] = rsqrtf(s * (1.f / 96.f) + 1e-5f);
  }
  __syncthreads();

  for (int idx = tid; idx < 32 * 96; idx += 256) {  // fold norm_w into tile
    int p = idx / 96, k = idx - p * 96;
    su[p * 100 + k] *= norm_w[k];
  }
  __syncthreads();

  const int p  = tid & 31;
  const int jb = tid >> 5;
  float xr[96];                      // register-resident xn row (reused 48x)
  {
    const float sc = sscale[p];
    #pragma unroll
    for (int k4 = 0; k4 < 24; ++k4) {
      float4 v = *(const float4*)&su[p * 100 + k4 * 4];
      xr[k4 * 4 + 0] = v.x * sc; xr[k4 * 4 + 1] = v.y * sc;
      xr[k4 * 4 + 2] = v.z * sc; xr[k4 * 4 + 3] = v.w * sc;
    }
  }
  for (int i = 0; i < 48; ++i) {
    int j = jb + (i << 3);
    const float4* wr = (const float4*)(W_in + j * 96);
    float acc = 0.f;
    #pragma unroll
    for (int k4 = 0; k4 < 24; ++k4) {
      float4 w = wr[k4];
      acc += w.x * xr[k4 * 4] + w.y * xr[k4 * 4 + 1] +
             w.z * xr[k4 * 4 + 2] + w.w * xr[k4 * 4 + 3];
    }
    sout[p * 385 + j] = acc;
  }
  __syncthreads();

  for (int idx = tid; idx < 32 * 384; idx += 256) {  // coalesced write-out
    int p2 = idx / 384, j2 = idx - p2 * 384;
    float v = sout[p2 * 385 + j2];
    int pos = base + p2;
    if (j2 < 192) xpre[pos * 192 + j2] = v;
    else          zbuf[pos * 192 + (j2 - 192)] = v;
  }
}

// ---------------------------------------------------------------------------
// K2: causal depthwise conv3 + bias + SiLU; dbc = x @ W_x.T (22 outs);
//     delta = softplus(dt @ W_dt.T + b_dt). One block = 32 positions.
// ---------------------------------------------------------------------------
__global__ __launch_bounds__(256) void k_conv_dbc(
    const float* __restrict__ xpre, const float* __restrict__ conv_w,
    const float* __restrict__ conv_b, const float* __restrict__ W_x,
    const float* __restrict__ W_dt, const float* __restrict__ b_dt,
    float* __restrict__ xpost, float* __restrict__ delta,
    float* __restrict__ bc)
{
  __shared__ float sxp[34 * 192];  // positions base-2 .. base+31
  __shared__ float sxo[32 * 192];  // post conv+silu
  __shared__ float sdt[32 * 6];
  const int tid  = threadIdx.x;
  const int base = blockIdx.x * 32;
  const int linb = base & 4095;    // l within batch

  for (int idx = tid; idx < 34 * 192; idx += 256) {
    int p = idx / 192, d = idx - p * 192;
    int l = linb + p - 2;
    sxp[idx] = (l >= 0) ? xpre[(base + p - 2) * 192 + d] : 0.f;
  }
  __syncthreads();

  for (int idx = tid; idx < 32 * 192; idx += 256) {
    int p = idx / 192, d = idx - p * 192;
    float acc = conv_b[d]
              + conv_w[d * 3 + 0] * sxp[(p + 0) * 192 + d]
              + conv_w[d * 3 + 1] * sxp[(p + 1) * 192 + d]
              + conv_w[d * 3 + 2] * sxp[(p + 2) * 192 + d];
    sxo[p * 192 + d] = acc / (1.f + __expf(-acc));   // silu
  }
  __syncthreads();

  for (int idx = tid; idx < 32 * 22; idx += 256) {   // dbc tile
    int p = idx / 22, jj = idx - p * 22;
    const float* wrow = W_x + jj * 192;
    const float* xrow = &sxo[p * 192];
    float acc = 0.f;
    #pragma unroll 8
    for (int d = 0; d < 192; ++d) acc += xrow[d] * wrow[d];
    if (jj < 6) sdt[p * 6 + jj] = acc;
    else        bc[(base + p) * 16 + (jj - 6)] = acc;  // B:0..7 C:8..15
  }
  __syncthreads();

  for (int idx = tid; idx < 32 * 192; idx += 256) {
    int p = idx / 192, d = idx - p * 192;
    const float* wd = W_dt + d * 6;
    const float* dtp = &sdt[p * 6];
    float acc = b_dt[d];
    #pragma unroll
    for (int r = 0; r < 6; ++r) acc += dtp[r] * wd[r];
    float sp = (acc > 20.f) ? acc : log1pf(__expf(acc));  // softplus
    int pos = base + p;
    delta[pos * 192 + d] = sp;
    xpost[pos * 192 + d] = sxo[p * 192 + d];
  }
}

// ---------------------------------------------------------------------------
// K3: chunked SSM scan. Block = (b, chunk); thread = channel d (192 threads).
// 8 states in registers. Emits local gated-y sum (atomic), and carries
// P (prod deltaA), Q (local final h), K (correction coeff) per (b,d,chunk,s).
// ---------------------------------------------------------------------------
__global__ __launch_bounds__(192) void k_scan(
    const float* __restrict__ xpost, const float* __restrict__ delta,
    const float* __restrict__ zbuf, const float* __restrict__ bc,
    const float* __restrict__ A_log, const float* __restrict__ D_ssm,
    float* __restrict__ Pc, float* __restrict__ Qc, float* __restrict__ Kc,
    float* __restrict__ ysum)
{
  const int blk = blockIdx.x;
  const int b   = blk >> 7;        // / NCHUNK
  const int c   = blk & 127;
  const int d   = threadIdx.x;
  __shared__ float sbc[CLEN * 16];
  const int base = b * LL + c * CLEN;

  for (int idx = d; idx < CLEN * 16; idx += 192) sbc[idx] = bc[base * 16 + idx];
  __syncthreads();

  float a[8], h[8], P[8], K[8];
  #pragma unroll
  for (int s = 0; s < 8; ++s) {
    a[s] = -__expf(A_log[d * 8 + s]);
    h[s] = 0.f; P[s] = 1.f; K[s] = 0.f;
  }
  const float Dd = D_ssm[d];
  float ys = 0.f;

  for (int i = 0; i < CLEN; ++i) {
    int g = (base + i) * 192 + d;
    float dl = delta[g], xv = xpost[g], zv = zbuf[g];
    float sz = zv / (1.f + __expf(-zv));   // silu(z)
    float dx = dl * xv;
    float yl = Dd * xv;
    #pragma unroll
    for (int s = 0; s < 8; ++s) {
      float dA = __expf(dl * a[s]);
      float Bs = sbc[i * 16 + s];
      float Cs = sbc[i * 16 + 8 + s];
      h[s] = dA * h[s] + dx * Bs;
      yl  += h[s] * Cs;
      P[s] *= dA;
      K[s] += P[s] * Cs * sz;
    }
    ys += yl * sz;
  }
  atomicAdd(&ysum[b * 192 + d], ys);
  const int cb = ((b * 192 + d) * NCHUNK + c) * 8;
  #pragma unroll
  for (int s = 0; s < 8; ++s) { Pc[cb + s] = P[s]; Qc[cb + s] = h[s]; Kc[cb + s] = K[s]; }
}

// ---------------------------------------------------------------------------
// K4: sequential combine over chunks. Thread = (b,d,s); 12288 threads.
// H_{c+1} = P_c*H_c + Q_c ; ycorr = sum_c K_c * H_c. Reduce over s, atomicAdd.
// ---------------------------------------------------------------------------
__global__ __launch_bounds__(256) void k_combine(
    const float* __restrict__ Pc, const float* __restrict__ Qc,
    const float* __restrict__ Kc, float* __restrict__ ysum)
{
  int t = blockIdx.x * 256 + threadIdx.x;
  if (t >= BB * 192 * 8) return;
  int s  = t & 7;
  int bd = t >> 3;
  int o0 = bd * NCHUNK * 8 + s;
  float H = 0.f, acc = 0.f;
  for (int c = 0; c < NCHUNK; ++c) {
    int o = o0 + c * 8;
    acc += Kc[o] * H;
    H = Pc[o] * H + Qc[o];
  }
  acc += __shfl_down(acc, 4);
  acc += __shfl_down(acc, 2);
  acc += __shfl_down(acc, 1);
  if (s == 0) atomicAdd(&ysum[bd], acc);
}

// ---------------------------------------------------------------------------
// K5: head. One block per batch.
// e = (usum + ysum@W_out.T)/L ; t = elu(tanh(e@fc_w.T+b)) ; mu/sigma.
// ---------------------------------------------------------------------------
__global__ __launch_bounds__(256) void k_head(
    const float* __restrict__ usum, const float* __restrict__ ysum,
    const float* __restrict__ W_out, const float* __restrict__ fc_w,
    const float* __restrict__ fc_b, const float* __restrict__ mu_w,
    const float* __restrict__ mu_b, const float* __restrict__ sg_w,
    const float* __restrict__ sg_b, float* __restrict__ out)
{
  const int b = blockIdx.x, tid = threadIdx.x;
  __shared__ float e[96];
  __shared__ float tb[256];
  if (tid < 96) {
    const float* wr = W_out + tid * 192;
    const float* yr = ysum + b * 192;
    float acc = usum[b * 96 + tid];
    #pragma unroll 8
    for (int d = 0; d < 192; ++d) acc += yr[d] * wr[d];
    e[tid] = acc * (1.f / (float)LL);
  }
  __syncthreads();
  {
    const float* wr = fc_w + tid * 96;
    float acc = fc_b[tid];
    #pragma unroll 8
    for (int j = 0; j < 96; ++j) acc += e[j] * wr[j];
    float th = tanhf(acc);
    tb[tid] = (th > 0.f) ? th : expm1f(th);          // elu
  }
  __syncthreads();
  if (tid < 64) {
    const float* wr = mu_w + tid * 256;
    float acc = mu_b[tid];
    #pragma unroll 8
    for (int i = 0; i < 256; ++i) acc += tb[i] * wr[i];
    out[b * 64 + tid] = acc;
  } else if (tid < 128) {
    int o = tid - 64;
    const float* wr = sg_w + o * 256;
    float acc = sg_b[o];
    #pragma unroll 8
    for (int i = 0; i < 256; ++i) acc += tb[i] * wr[i];
    float el = (acc > 0.f) ? acc : expm1f(acc);
    out[BB * 64 + b * 64 + o] = el + 1.f + 1e-14f;
  }
}

// ---------------------------------------------------------------------------
extern "C" void kernel_launch(void* const* d_in, const int* in_sizes, int n_in,
                              void* d_out, int out_size, void* d_ws, size_t ws_size,
                              hipStream_t stream)
{
  const float* input  = (const float*)d_in[0];
  const float* norm_w = (const float*)d_in[1];
  const float* W_in   = (const float*)d_in[2];
  const float* conv_w = (const float*)d_in[3];
  const float* conv_b = (const float*)d_in[4];
  const float* W_x    = (const float*)d_in[5];
  const float* W_dt   = (const float*)d_in[6];
  const float* b_dt   = (const float*)d_in[7];
  const float* A_log  = (const float*)d_in[8];
  const float* D_ssm  = (const float*)d_in[9];
  const float* W_out  = (const float*)d_in[10];
  const float* fc_w   = (const float*)d_in[11];
  const float* fc_b   = (const float*)d_in[12];
  const float* mu_w   = (const float*)d_in[13];
  const float* mu_b   = (const float*)d_in[14];
  const float* sg_w   = (const float*)d_in[15];
  const float* sg_b   = (const float*)d_in[16];

  float* ws  = (float*)d_ws;
  float* out = (float*)d_out;

  // zero the accumulators (ysum then usum are contiguous)
  hipMemsetAsync(ws + YSUM_OFF, 0, (BB * 192 + BB * 96) * sizeof(float), stream);

  k_rms_gemm<<<BLT / 32, 256, 0, stream>>>(input, norm_w, W_in,
      ws + XPRE_OFF, ws + Z_OFF, ws + USUM_OFF);
  k_conv_dbc<<<BLT / 32, 256, 0, stream>>>(ws + XPRE_OFF, conv_w, conv_b,
      W_x, W_dt, b_dt, ws + XPOST_OFF, ws + DELTA_OFF, ws + BC_OFF);
  k_scan<<<BB * NCHUNK, 192, 0, stream>>>(ws + XPOST_OFF, ws + DELTA_OFF,
      ws + Z_OFF, ws + BC_OFF, A_log, D_ssm,
      ws + P_OFF, ws + Q_OFF, ws + KC_OFF, ws + YSUM_OFF);
  k_combine<<<48, 256, 0, stream>>>(ws + P_OFF, ws + Q_OFF, ws + KC_OFF,
      ws + YSUM_OFF);
  k_head<<<BB, 256, 0, stream>>>(ws + USUM_OFF, ws + YSUM_OFF, W_out,
      fc_w, fc_b, mu_w, mu_b, sg_w, sg_b, out);
}

// Round 2
// 250.282 us; speedup vs baseline: 1.6287x; 1.6287x over previous
//
#include <hip/hip_runtime.h>
#include <hip/hip_bf16.h>

// Problem constants
#define DM   96
#define DI   192
#define BB   8
#define LL   4096
#define BLT  32768   // B*L
#define NCHUNK 128
#define CLEN   32    // chunk length; NCHUNK*CLEN == LL
#define NSEG   8
#define SEGC   16    // NSEG*SEGC == NCHUNK

typedef __bf16 bf16_t;
typedef __attribute__((ext_vector_type(8))) __bf16 bf16x8;
typedef __attribute__((ext_vector_type(4))) float f32x4;

// Workspace layout (float offsets)
#define XPRE_OFF   0u          // [B*L,192] x pre-conv (dead after K2; reused by comb1)
#define Z_OFF      6291456u    // [B*L,192] z (gate)
#define XPOST_OFF  12582912u   // [B*L,192] x post conv+silu
#define DELTA_OFF  18874368u   // [B*L,192] softplus delta
#define BC_OFF     25165824u   // [B*L,16]  B(8) then C(8)
#define P_OFF      25690112u   // [B,NCHUNK,192,8] chunk prod deltaA (also Wbf16 home pre-K3)
#define Q_OFF      27262976u   // [B,NCHUNK,192,8] chunk local final h
#define KC_OFF     28835840u   // [B,NCHUNK,192,8] correction coeff
#define YSUM_OFF   30408704u   // [B,192]
#define USUM_OFF   30410240u   // [B,96]
// comb1 outputs overlay XPRE (dead by then): 4 arrays of 98304 floats
#define PG_OFF     (XPRE_OFF + 0u)
#define QG_OFF     (XPRE_OFF + 98304u)
#define GG_OFF     (XPRE_OFF + 196608u)
#define KG_OFF     (XPRE_OFF + 294912u)

// ---------------------------------------------------------------------------
// K0: convert W_in fp32 -> bf16
// ---------------------------------------------------------------------------
__global__ __launch_bounds__(256) void k_cvt(const float* __restrict__ w,
                                             bf16_t* __restrict__ o) {
  int i = blockIdx.x * 256 + threadIdx.x;
  if (i < 384 * 96) o[i] = (bf16_t)w[i];
}

// ---------------------------------------------------------------------------
// K1: RMSNorm + xz = xn @ W_in.T via bf16 MFMA. Block = 64 rows, 4 waves.
// Wave w owns output cols [96w, 96w+96) = 6 n-tiles; 4 m-tiles of 16.
// Layouts (measured, learn_hip m89/m120): A[m=lane&15][k=quad*8+j],
// B[k=quad*8+j][n=lane&15], C col=lane&15 row=quad*4+reg.
// ---------------------------------------------------------------------------
__global__ __launch_bounds__(256) void k1_mfma(
    const float* __restrict__ u, const float* __restrict__ norm_w,
    const bf16_t* __restrict__ Wbf, float* __restrict__ xpre,
    float* __restrict__ zbuf, float* __restrict__ usum)
{
  __shared__ __align__(16) float su[64 * 100];   // stride 100: bank-spread, 16B-aligned
  __shared__ __align__(16) bf16_t sa[64 * 104];  // bf16 A tile, stride 104
  __shared__ float sscale[64];
  const int tid  = threadIdx.x;
  const int base = blockIdx.x * 64;
  const int b    = base >> 12;
  const int wv   = tid >> 6, lane = tid & 63;
  const int q    = lane >> 4, nlo = lane & 15;

  // stage u tile (fully coalesced float4)
  for (int i = tid; i < 64 * 24; i += 256) {
    int p = i / 24, k4 = (i - p * 24) * 4;
    *(float4*)&su[p * 100 + k4] = *(const float4*)&u[(base + p) * 96 + k4];
  }

  // B fragments: 6 n-tiles x 3 k-steps, from global (L2-resident, 72 KB total)
  bf16x8 Bf[6][3];
  #pragma unroll
  for (int nt = 0; nt < 6; ++nt)
    #pragma unroll
    for (int ks = 0; ks < 3; ++ks)
      Bf[nt][ks] = *(const bf16x8*)&Wbf[(wv * 96 + nt * 16 + nlo) * 96 + ks * 32 + q * 8];

  __syncthreads();

  if (tid < 64) {                     // per-row rms scale
    float s = 0.f;
    #pragma unroll
    for (int k4 = 0; k4 < 24; ++k4) {
      float4 v = *(const float4*)&su[tid * 100 + k4 * 4];
      s += v.x * v.x + v.y * v.y + v.z * v.z + v.w * v.w;
    }
    sscale[tid] = rsqrtf(s * (1.f / 96.f) + 1e-5f);
  } else if (tid >= 128 && tid < 224) {  // raw-u column sums (for e.mean)
    int k = tid - 128;
    float s = 0.f;
    for (int p = 0; p < 64; ++p) s += su[p * 100 + k];
    atomicAdd(&usum[b * 96 + k], s);
  }
  __syncthreads();

  // convert to bf16 with scale * norm_w folded in
  for (int i = tid; i < 64 * 48; i += 256) {
    int p = i / 48, k2 = (i - p * 48) * 2;
    float sc = sscale[p];
    sa[p * 104 + k2]     = (bf16_t)(su[p * 100 + k2] * sc * norm_w[k2]);
    sa[p * 104 + k2 + 1] = (bf16_t)(su[p * 100 + k2 + 1] * sc * norm_w[k2 + 1]);
  }
  __syncthreads();

  const int n0 = wv * 96;
  #pragma unroll
  for (int mt = 0; mt < 4; ++mt) {
    const int arow = (mt * 16 + nlo) * 104 + q * 8;
    bf16x8 A0 = *(const bf16x8*)&sa[arow];
    bf16x8 A1 = *(const bf16x8*)&sa[arow + 32];
    bf16x8 A2 = *(const bf16x8*)&sa[arow + 64];
    #pragma unroll
    for (int nt = 0; nt < 6; ++nt) {
      f32x4 acc = {0.f, 0.f, 0.f, 0.f};
      acc = __builtin_amdgcn_mfma_f32_16x16x32_bf16(A0, Bf[nt][0], acc, 0, 0, 0);
      acc = __builtin_amdgcn_mfma_f32_16x16x32_bf16(A1, Bf[nt][1], acc, 0, 0, 0);
      acc = __builtin_amdgcn_mfma_f32_16x16x32_bf16(A2, Bf[nt][2], acc, 0, 0, 0);
      int j = n0 + nt * 16 + nlo;
      int row0 = base + mt * 16 + q * 4;
      float* dst = (j < 192) ? xpre : zbuf;
      int jj = (j < 192) ? j : j - 192;
      #pragma unroll
      for (int r = 0; r < 4; ++r)
        dst[(row0 + r) * 192 + jj] = acc[r];
    }
  }
}

// ---------------------------------------------------------------------------
// K2: causal depthwise conv3 + SiLU; dbc = x @ W_x.T; delta = softplus(...).
// One block = 32 positions, vectorized float4 throughout.
// ---------------------------------------------------------------------------
__global__ __launch_bounds__(256) void k_conv_dbc(
    const float* __restrict__ xpre, const float* __restrict__ conv_w,
    const float* __restrict__ conv_b, const float* __restrict__ W_x,
    const float* __restrict__ W_dt, const float* __restrict__ b_dt,
    float* __restrict__ xpost, float* __restrict__ delta,
    float* __restrict__ bc)
{
  __shared__ __align__(16) float sxp[34 * 192];
  __shared__ __align__(16) float sxo[32 * 192];
  __shared__ float sdt[32 * 8];
  const int tid  = threadIdx.x;
  const int base = blockIdx.x * 32;
  const int linb = base & 4095;

  for (int i = tid; i < 34 * 48; i += 256) {
    int p = i / 48, d4 = (i - p * 48) * 4;
    int l = linb + p - 2;
    float4 v = (l >= 0) ? *(const float4*)&xpre[(base + p - 2) * 192 + d4]
                        : make_float4(0.f, 0.f, 0.f, 0.f);
    *(float4*)&sxp[p * 192 + d4] = v;
  }
  __syncthreads();

  for (int i = tid; i < 32 * 48; i += 256) {
    int p = i / 48, d4 = (i - p * 48) * 4;
    float4 x0 = *(const float4*)&sxp[(p + 0) * 192 + d4];
    float4 x1 = *(const float4*)&sxp[(p + 1) * 192 + d4];
    float4 x2 = *(const float4*)&sxp[(p + 2) * 192 + d4];
    float4 cb = *(const float4*)&conv_b[d4];
    float4 c0 = *(const float4*)&conv_w[d4 * 3];
    float4 c1 = *(const float4*)&conv_w[d4 * 3 + 4];
    float4 c2 = *(const float4*)&conv_w[d4 * 3 + 8];
    float4 r;
    r.x = cb.x + c0.x * x0.x + c0.y * x1.x + c0.z * x2.x;
    r.y = cb.y + c0.w * x0.y + c1.x * x1.y + c1.y * x2.y;
    r.z = cb.z + c1.z * x0.z + c1.w * x1.z + c2.x * x2.z;
    r.w = cb.w + c2.y * x0.w + c2.z * x1.w + c2.w * x2.w;
    r.x = r.x / (1.f + __expf(-r.x));
    r.y = r.y / (1.f + __expf(-r.y));
    r.z = r.z / (1.f + __expf(-r.z));
    r.w = r.w / (1.f + __expf(-r.w));
    *(float4*)&sxo[p * 192 + d4] = r;
  }
  __syncthreads();

  {  // dbc: p = tid>>3, q = tid&7 handles j in {q, q+8, q+16} (j<22)
    int p = tid >> 3, qq = tid & 7;
    const float4* xr = (const float4*)&sxo[p * 192];
    const float4* w0 = (const float4*)&W_x[qq * 192];
    const float4* w1 = (const float4*)&W_x[(qq + 8) * 192];
    const float4* w2 = (qq < 6) ? (const float4*)&W_x[(qq + 16) * 192] : w0;
    float a0 = 0.f, a1 = 0.f, a2 = 0.f;
    #pragma unroll 8
    for (int k = 0; k < 48; ++k) {
      float4 x = xr[k];
      float4 u0 = w0[k], u1 = w1[k], u2 = w2[k];
      a0 += x.x * u0.x + x.y * u0.y + x.z * u0.z + x.w * u0.w;
      a1 += x.x * u1.x + x.y * u1.y + x.z * u1.z + x.w * u1.w;
      a2 += x.x * u2.x + x.y * u2.y + x.z * u2.z + x.w * u2.w;
    }
    int pos = base + p;
    if (qq < 6) {
      sdt[p * 8 + qq] = a0;
      bc[pos * 16 + 2 + qq]  = a1;   // B(qq+2)
      bc[pos * 16 + 10 + qq] = a2;   // C(qq+2)
    } else if (qq == 6) {
      bc[pos * 16 + 0] = a0;         // B0
      bc[pos * 16 + 8] = a1;         // C0
    } else {
      bc[pos * 16 + 1] = a0;         // B1
      bc[pos * 16 + 9] = a1;         // C1
    }
  }
  __syncthreads();

  for (int i = tid; i < 32 * 48; i += 256) {
    int p = i / 48, d4 = (i - p * 48) * 4;
    float4 bd = *(const float4*)&b_dt[d4];
    float dtv[6];
    #pragma unroll
    for (int r = 0; r < 6; ++r) dtv[r] = sdt[p * 8 + r];
    float4 acc = bd;
    #pragma unroll
    for (int r = 0; r < 6; ++r) {
      acc.x += dtv[r] * W_dt[(d4 + 0) * 6 + r];
      acc.y += dtv[r] * W_dt[(d4 + 1) * 6 + r];
      acc.z += dtv[r] * W_dt[(d4 + 2) * 6 + r];
      acc.w += dtv[r] * W_dt[(d4 + 3) * 6 + r];
    }
    float4 sp;
    sp.x = (acc.x > 20.f) ? acc.x : log1pf(__expf(acc.x));
    sp.y = (acc.y > 20.f) ? acc.y : log1pf(__expf(acc.y));
    sp.z = (acc.z > 20.f) ? acc.z : log1pf(__expf(acc.z));
    sp.w = (acc.w > 20.f) ? acc.w : log1pf(__expf(acc.w));
    int pos = base + p;
    *(float4*)&delta[pos * 192 + d4] = sp;
    *(float4*)&xpost[pos * 192 + d4] = *(const float4*)&sxo[p * 192 + d4];
  }
}

// ---------------------------------------------------------------------------
// K3: chunked SSM scan. Block = (b, chunk); thread = channel d.
// Carries in [b][c][d][s] layout (coalesced writes here, coalesced reads in K4a).
// ---------------------------------------------------------------------------
__global__ __launch_bounds__(192) void k_scan(
    const float* __restrict__ xpost, const float* __restrict__ delta,
    const float* __restrict__ zbuf, const float* __restrict__ bc,
    const float* __restrict__ A_log, const float* __restrict__ D_ssm,
    float* __restrict__ Pc, float* __restrict__ Qc, float* __restrict__ Kc,
    float* __restrict__ ysum)
{
  const int blk = blockIdx.x;
  const int b = blk >> 7, c = blk & 127;
  const int d = threadIdx.x;
  __shared__ __align__(16) float sbc[CLEN * 16];
  const int base = b * LL + c * CLEN;

  for (int i = d; i < CLEN * 4; i += 192)
    *(float4*)&sbc[i * 4] = *(const float4*)&bc[base * 16 + i * 4];
  __syncthreads();

  float a[8], h[8], P[8], K[8];
  {
    float4 al0 = *(const float4*)&A_log[d * 8];
    float4 al1 = *(const float4*)&A_log[d * 8 + 4];
    a[0] = -__expf(al0.x); a[1] = -__expf(al0.y); a[2] = -__expf(al0.z); a[3] = -__expf(al0.w);
    a[4] = -__expf(al1.x); a[5] = -__expf(al1.y); a[6] = -__expf(al1.z); a[7] = -__expf(al1.w);
  }
  #pragma unroll
  for (int s = 0; s < 8; ++s) { h[s] = 0.f; P[s] = 1.f; K[s] = 0.f; }
  const float Dd = D_ssm[d];
  float ys = 0.f;

  for (int i = 0; i < CLEN; ++i) {
    int g = (base + i) * 192 + d;
    float dl = delta[g], xv = xpost[g], zv = zbuf[g];
    float sz = zv / (1.f + __expf(-zv));
    float dx = dl * xv;
    float yl = Dd * xv;
    float4 B0 = *(const float4*)&sbc[i * 16];
    float4 B1 = *(const float4*)&sbc[i * 16 + 4];
    float4 C0 = *(const float4*)&sbc[i * 16 + 8];
    float4 C1 = *(const float4*)&sbc[i * 16 + 12];
    float Bv[8] = {B0.x, B0.y, B0.z, B0.w, B1.x, B1.y, B1.z, B1.w};
    float Cv[8] = {C0.x, C0.y, C0.z, C0.w, C1.x, C1.y, C1.z, C1.w};
    #pragma unroll
    for (int s = 0; s < 8; ++s) {
      float dA = __expf(dl * a[s]);
      h[s] = dA * h[s] + dx * Bv[s];
      yl  += h[s] * Cv[s];
      P[s] *= dA;
      K[s] += P[s] * Cv[s] * sz;
    }
    ys += yl * sz;
  }
  atomicAdd(&ysum[b * 192 + d], ys);
  const int cb = ((b * NCHUNK + c) * 192 + d) * 8;
  *(float4*)&Pc[cb]     = make_float4(P[0], P[1], P[2], P[3]);
  *(float4*)&Pc[cb + 4] = make_float4(P[4], P[5], P[6], P[7]);
  *(float4*)&Qc[cb]     = make_float4(h[0], h[1], h[2], h[3]);
  *(float4*)&Qc[cb + 4] = make_float4(h[4], h[5], h[6], h[7]);
  *(float4*)&Kc[cb]     = make_float4(K[0], K[1], K[2], K[3]);
  *(float4*)&Kc[cb + 4] = make_float4(K[4], K[5], K[6], K[7]);
}

// ---------------------------------------------------------------------------
// K4a: level-1 combine. Thread = (b,seg,d,s); 98304 threads, 16 serial chunks.
// Segment with entry state H0: contribution = G*H0 + Khat; exit = Phat*H0 + Qhat.
// ---------------------------------------------------------------------------
__global__ __launch_bounds__(256) void k_comb1(
    const float* __restrict__ Pc, const float* __restrict__ Qc,
    const float* __restrict__ Kc, float* __restrict__ Pg,
    float* __restrict__ Qg, float* __restrict__ Gg, float* __restrict__ Kg)
{
  int t = blockIdx.x * 256 + threadIdx.x;
  if (t >= BB * NSEG * 192 * 8) return;
  int s = t & 7;
  int rr = t >> 3;
  int d = rr % 192;
  int bs = rr / 192;
  int seg = bs & (NSEG - 1);
  int b = bs >> 3;
  float Pp = 1.f, Hl = 0.f, G = 0.f, Kh = 0.f;
  for (int ci = 0; ci < SEGC; ++ci) {
    int c = seg * SEGC + ci;
    int o = ((b * NCHUNK + c) * 192 + d) * 8 + s;
    float pv = Pc[o], qv = Qc[o], kv = Kc[o];
    G  += kv * Pp;
    Kh += kv * Hl;
    Hl = pv * Hl + qv;
    Pp *= pv;
  }
  Pg[t] = Pp; Qg[t] = Hl; Gg[t] = G; Kg[t] = Kh;
}

// ---------------------------------------------------------------------------
// K4b: level-2 combine, 8 segments sequential per (b,d,s); reduce s; atomicAdd.
// ---------------------------------------------------------------------------
__global__ __launch_bounds__(256) void k_comb2(
    const float* __restrict__ Pg, const float* __restrict__ Qg,
    const float* __restrict__ Gg, const float* __restrict__ Kg,
    float* __restrict__ ysum)
{
  int t = blockIdx.x * 256 + threadIdx.x;
  if (t >= BB * 192 * 8) return;
  int s = t & 7;
  int rr = t >> 3;
  int d = rr % 192;
  int b = rr / 192;
  float H = 0.f, acc = 0.f;
  for (int seg = 0; seg < NSEG; ++seg) {
    int o = ((b * NSEG + seg) * 192 + d) * 8 + s;
    acc += Gg[o] * H + Kg[o];
    H = Pg[o] * H + Qg[o];
  }
  acc += __shfl_down(acc, 4);
  acc += __shfl_down(acc, 2);
  acc += __shfl_down(acc, 1);
  if (s == 0) atomicAdd(&ysum[b * 192 + d], acc);
}

// ---------------------------------------------------------------------------
// K5: head. One block per batch.
// ---------------------------------------------------------------------------
__global__ __launch_bounds__(256) void k_head(
    const float* __restrict__ usum, const float* __restrict__ ysum,
    const float* __restrict__ W_out, const float* __restrict__ fc_w,
    const float* __restrict__ fc_b, const float* __restrict__ mu_w,
    const float* __restrict__ mu_b, const float* __restrict__ sg_w,
    const float* __restrict__ sg_b, float* __restrict__ out)
{
  const int b = blockIdx.x, tid = threadIdx.x;
  __shared__ float e[96];
  __shared__ float tb[256];
  if (tid < 96) {
    const float* wr = W_out + tid * 192;
    const float* yr = ysum + b * 192;
    float acc = usum[b * 96 + tid];
    #pragma unroll 8
    for (int d = 0; d < 192; ++d) acc += yr[d] * wr[d];
    e[tid] = acc * (1.f / (float)LL);
  }
  __syncthreads();
  {
    const float* wr = fc_w + tid * 96;
    float acc = fc_b[tid];
    #pragma unroll 8
    for (int j = 0; j < 96; ++j) acc += e[j] * wr[j];
    float th = tanhf(acc);
    tb[tid] = (th > 0.f) ? th : expm1f(th);
  }
  __syncthreads();
  if (tid < 64) {
    const float* wr = mu_w + tid * 256;
    float acc = mu_b[tid];
    #pragma unroll 8
    for (int i = 0; i < 256; ++i) acc += tb[i] * wr[i];
    out[b * 64 + tid] = acc;
  } else if (tid < 128) {
    int o = tid - 64;
    const float* wr = sg_w + o * 256;
    float acc = sg_b[o];
    #pragma unroll 8
    for (int i = 0; i < 256; ++i) acc += tb[i] * wr[i];
    float el = (acc > 0.f) ? acc : expm1f(acc);
    out[BB * 64 + b * 64 + o] = el + 1.f + 1e-14f;
  }
}

// ---------------------------------------------------------------------------
extern "C" void kernel_launch(void* const* d_in, const int* in_sizes, int n_in,
                              void* d_out, int out_size, void* d_ws, size_t ws_size,
                              hipStream_t stream)
{
  const float* input  = (const float*)d_in[0];
  const float* norm_w = (const float*)d_in[1];
  const float* W_in   = (const float*)d_in[2];
  const float* conv_w = (const float*)d_in[3];
  const float* conv_b = (const float*)d_in[4];
  const float* W_x    = (const float*)d_in[5];
  const float* W_dt   = (const float*)d_in[6];
  const float* b_dt   = (const float*)d_in[7];
  const float* A_log  = (const float*)d_in[8];
  const float* D_ssm  = (const float*)d_in[9];
  const float* W_out  = (const float*)d_in[10];
  const float* fc_w   = (const float*)d_in[11];
  const float* fc_b   = (const float*)d_in[12];
  const float* mu_w   = (const float*)d_in[13];
  const float* mu_b   = (const float*)d_in[14];
  const float* sg_w   = (const float*)d_in[15];
  const float* sg_b   = (const float*)d_in[16];

  float* ws  = (float*)d_ws;
  float* out = (float*)d_out;
  bf16_t* Wbf = (bf16_t*)(ws + P_OFF);   // P region is only written later by K3

  hipMemsetAsync(ws + YSUM_OFF, 0, (BB * 192 + BB * 96) * sizeof(float), stream);

  k_cvt<<<144, 256, 0, stream>>>(W_in, Wbf);
  k1_mfma<<<BLT / 64, 256, 0, stream>>>(input, norm_w, Wbf,
      ws + XPRE_OFF, ws + Z_OFF, ws + USUM_OFF);
  k_conv_dbc<<<BLT / 32, 256, 0, stream>>>(ws + XPRE_OFF, conv_w, conv_b,
      W_x, W_dt, b_dt, ws + XPOST_OFF, ws + DELTA_OFF, ws + BC_OFF);
  k_scan<<<BB * NCHUNK, 192, 0, stream>>>(ws + XPOST_OFF, ws + DELTA_OFF,
      ws + Z_OFF, ws + BC_OFF, A_log, D_ssm,
      ws + P_OFF, ws + Q_OFF, ws + KC_OFF, ws + YSUM_OFF);
  k_comb1<<<(BB * NSEG * 192 * 8) / 256, 256, 0, stream>>>(
      ws + P_OFF, ws + Q_OFF, ws + KC_OFF,
      ws + PG_OFF, ws + QG_OFF, ws + GG_OFF, ws + KG_OFF);
  k_comb2<<<(BB * 192 * 8) / 256, 256, 0, stream>>>(
      ws + PG_OFF, ws + QG_OFF, ws + GG_OFF, ws + KG_OFF, ws + YSUM_OFF);
  k_head<<<BB, 256, 0, stream>>>(ws + USUM_OFF, ws + YSUM_OFF, W_out,
      fc_w, fc_b, mu_w, mu_b, sg_w, sg_b, out);
}

// Round 3
// 235.005 us; speedup vs baseline: 1.7346x; 1.0650x over previous
//
#include <hip/hip_runtime.h>
#include <hip/hip_bf16.h>

// Problem constants
#define DM   96
#define DI   192
#define BB   8
#define LL   4096
#define NCHUNK 128
#define CLEN   32
#define NSEG   8
#define SEGC   16

typedef __bf16 bf16_t;
typedef __attribute__((ext_vector_type(8))) __bf16 bf16x8;
typedef __attribute__((ext_vector_type(4))) float f32x4;

// Workspace layout (float offsets)
#define P_OFF    0u         // [B,128,192,8]
#define Q_OFF    786432u
#define KC_OFF   1572864u
#define PG_OFF   2359296u   // [B,8,192,8]
#define QG_OFF   2457600u
#define GG_OFF   2555904u
#define KG_OFF   2654208u
#define YSUM_OFF 2752512u   // [B,192]
#define USUM_OFF 2754048u   // [B,96]
#define WBF_OFF  2754816u   // bf16 W_in [384][96] (36864 bf16 = 18432 floats)

// LDS layout (bytes). su (fp32 u tile) aliases sxo (bf16 conv output) —
// su dead after the bf16 A-tile conversion, sxo written after MFMA barrier.
#define L_SU   0u        // 34*100*4 = 13600  | sxo: 32*200*2 = 12800
#define L_SA   13600u    // 48*104*2 = 9984   (16B-aligned rows, stride 208B=13x16)
#define L_SXH  23584u    // 34*198*2 = 13464  (in-proj x half, bf16)
#define L_SZH  37056u    // 32*198*2 = 12672  (silu(z), owned rows only)
#define L_SBC  49728u    // 32*16*4  = 2048
#define L_SDT  51776u    // 32*8*4   = 1024
#define L_SSC  52800u    // 34*4     = 136
#define L_TOT  52944u

// ---------------------------------------------------------------------------
__global__ __launch_bounds__(256) void k_cvt(const float* __restrict__ w,
                                             bf16_t* __restrict__ o) {
  int i = blockIdx.x * 256 + threadIdx.x;
  if (i < 384 * 96) o[i] = (bf16_t)w[i];
}

// ---------------------------------------------------------------------------
// Fused: rmsnorm + in-proj MFMA + conv3/silu + dbc + delta + chunk scan.
// Block = (b, chunk of 32 positions); 256 threads (4 waves).
// ---------------------------------------------------------------------------
__global__ __launch_bounds__(256) void k_fused(
    const float* __restrict__ u, const float* __restrict__ norm_w,
    const bf16_t* __restrict__ Wbf, const float* __restrict__ conv_w,
    const float* __restrict__ conv_b, const float* __restrict__ W_x,
    const float* __restrict__ W_dt, const float* __restrict__ b_dt,
    const float* __restrict__ A_log, const float* __restrict__ D_ssm,
    float* __restrict__ Pc, float* __restrict__ Qc, float* __restrict__ Kc,
    float* __restrict__ ysum, float* __restrict__ usum)
{
  __shared__ __align__(16) char lds[L_TOT];
  float*  su  = (float*)(lds + L_SU);
  bf16_t* sxo = (bf16_t*)(lds + L_SU);
  bf16_t* sa  = (bf16_t*)(lds + L_SA);
  bf16_t* sxh = (bf16_t*)(lds + L_SXH);
  bf16_t* szh = (bf16_t*)(lds + L_SZH);
  float*  sbc = (float*)(lds + L_SBC);
  float*  sdt = (float*)(lds + L_SDT);
  float*  ssc = (float*)(lds + L_SSC);

  const int tid = threadIdx.x;
  const int b   = blockIdx.x >> 7;      // / NCHUNK
  const int c   = blockIdx.x & 127;
  const int wv  = tid >> 6, lane = tid & 63;
  const int q   = lane >> 4, nlo = lane & 15;
  const int l0  = c * CLEN - 2;         // batch-local position of su row 0

  // --- B fragments first (global, L2/L3-resident; overlap with staging) ---
  bf16x8 Bf[6][3];
  #pragma unroll
  for (int nt = 0; nt < 6; ++nt)
    #pragma unroll
    for (int ks = 0; ks < 3; ++ks)
      Bf[nt][ks] = *(const bf16x8*)&Wbf[(wv * 96 + nt * 16 + nlo) * 96 + ks * 32 + q * 8];

  // --- stage u rows l0..l0+33 (zeros for l<0, chunk 0 halo) ---
  for (int i = tid; i < 34 * 24; i += 256) {
    int p = i / 24, k4 = (i - p * 24) * 4;
    int l = l0 + p;
    float4 v = (l >= 0) ? *(const float4*)&u[(b * LL + l) * 96 + k4]
                        : make_float4(0.f, 0.f, 0.f, 0.f);
    *(float4*)&su[p * 100 + k4] = v;
  }
  __syncthreads();

  // --- rms scales (34 rows) + raw-u column sums over owned rows 2..33 ---
  if (tid < 34) {
    float s = 0.f;
    #pragma unroll
    for (int k4 = 0; k4 < 24; ++k4) {
      float4 v = *(const float4*)&su[tid * 100 + k4 * 4];
      s += v.x * v.x + v.y * v.y + v.z * v.z + v.w * v.w;
    }
    ssc[tid] = rsqrtf(s * (1.f / 96.f) + 1e-5f);
  } else if (tid >= 64 && tid < 160) {
    int k = tid - 64;
    float s = 0.f;
    #pragma unroll 8
    for (int p = 0; p < 32; ++p) s += su[(p + 2) * 100 + k];
    atomicAdd(&usum[b * 96 + k], s);
  }
  __syncthreads();

  // --- bf16 A tile (scale * norm_w folded); zero pad rows 34..47 ---
  for (int i = tid; i < 34 * 48; i += 256) {
    int p = i / 48, k2 = (i - p * 48) * 2;
    float sc = ssc[p];
    sa[p * 104 + k2]     = (bf16_t)(su[p * 100 + k2] * sc * norm_w[k2]);
    sa[p * 104 + k2 + 1] = (bf16_t)(su[p * 100 + k2 + 1] * sc * norm_w[k2 + 1]);
  }
  for (int i = tid; i < 14 * 96; i += 256) {
    int p = 34 + i / 96, k = i - (i / 96) * 96;
    sa[p * 104 + k] = (bf16_t)0.f;
  }
  __syncthreads();

  // --- MFMA in-proj: 3 m-tiles x (per wave) 6 n-tiles x 3 k-steps ---
  #pragma unroll
  for (int mt = 0; mt < 3; ++mt) {
    const int arow = (mt * 16 + nlo) * 104 + q * 8;
    bf16x8 A0 = *(const bf16x8*)&sa[arow];
    bf16x8 A1 = *(const bf16x8*)&sa[arow + 32];
    bf16x8 A2 = *(const bf16x8*)&sa[arow + 64];
    #pragma unroll
    for (int nt = 0; nt < 6; ++nt) {
      f32x4 acc = {0.f, 0.f, 0.f, 0.f};
      acc = __builtin_amdgcn_mfma_f32_16x16x32_bf16(A0, Bf[nt][0], acc, 0, 0, 0);
      acc = __builtin_amdgcn_mfma_f32_16x16x32_bf16(A1, Bf[nt][1], acc, 0, 0, 0);
      acc = __builtin_amdgcn_mfma_f32_16x16x32_bf16(A2, Bf[nt][2], acc, 0, 0, 0);
      int j = wv * 96 + nt * 16 + nlo;
      int row0 = mt * 16 + q * 4;
      if (j < 192) {
        #pragma unroll
        for (int r = 0; r < 4; ++r) {
          int row = row0 + r;
          if (row < 34) sxh[row * 198 + j] = (bf16_t)acc[r];
        }
      } else {
        int jj = j - 192;
        #pragma unroll
        for (int r = 0; r < 4; ++r) {
          int row = row0 + r;
          if (row >= 2 && row < 34) {
            float v = acc[r];
            szh[(row - 2) * 198 + jj] = (bf16_t)(v / (1.f + __expf(-v)));
          }
        }
      }
    }
  }
  __syncthreads();

  // --- causal conv3 + SiLU -> sxo (overlays dead su) ---
  for (int i = tid; i < 32 * 192; i += 256) {
    int p = i / 192, dd = i - p * 192;
    float x0 = (float)sxh[(p + 0) * 198 + dd];
    float x1 = (float)sxh[(p + 1) * 198 + dd];
    float x2 = (float)sxh[(p + 2) * 198 + dd];
    float r = conv_b[dd] + conv_w[dd * 3] * x0 + conv_w[dd * 3 + 1] * x1
            + conv_w[dd * 3 + 2] * x2;
    sxo[p * 200 + dd] = (bf16_t)(r / (1.f + __expf(-r)));
  }
  __syncthreads();

  // --- dbc = x' @ W_x.T : thread (p=tid>>3, qq=tid&7) -> j in {qq,qq+8,qq+16} ---
  {
    int p = tid >> 3, qq = tid & 7;
    const bf16_t* xr = &sxo[p * 200];
    const float4* w0 = (const float4*)&W_x[qq * 192];
    const float4* w1 = (const float4*)&W_x[(qq + 8) * 192];
    const float4* w2 = (qq < 6) ? (const float4*)&W_x[(qq + 16) * 192] : w0;
    float a0 = 0.f, a1 = 0.f, a2 = 0.f, b0 = 0.f, b1 = 0.f, b2 = 0.f;
    #pragma unroll 4
    for (int k8 = 0; k8 < 24; k8 += 2) {
      bf16x8 xa = *(const bf16x8*)&xr[k8 * 8];
      bf16x8 xb = *(const bf16x8*)&xr[k8 * 8 + 8];
      #pragma unroll
      for (int h = 0; h < 2; ++h) {
        float4 u0 = w0[k8 * 2 + h], u1 = w1[k8 * 2 + h], u2 = w2[k8 * 2 + h];
        float xf0 = (float)xa[h * 4], xf1 = (float)xa[h * 4 + 1];
        float xf2 = (float)xa[h * 4 + 2], xf3 = (float)xa[h * 4 + 3];
        a0 += xf0 * u0.x + xf1 * u0.y + xf2 * u0.z + xf3 * u0.w;
        a1 += xf0 * u1.x + xf1 * u1.y + xf2 * u1.z + xf3 * u1.w;
        a2 += xf0 * u2.x + xf1 * u2.y + xf2 * u2.z + xf3 * u2.w;
      }
      #pragma unroll
      for (int h = 0; h < 2; ++h) {
        float4 u0 = w0[k8 * 2 + 2 + h], u1 = w1[k8 * 2 + 2 + h], u2 = w2[k8 * 2 + 2 + h];
        float xf0 = (float)xb[h * 4], xf1 = (float)xb[h * 4 + 1];
        float xf2 = (float)xb[h * 4 + 2], xf3 = (float)xb[h * 4 + 3];
        b0 += xf0 * u0.x + xf1 * u0.y + xf2 * u0.z + xf3 * u0.w;
        b1 += xf0 * u1.x + xf1 * u1.y + xf2 * u1.z + xf3 * u1.w;
        b2 += xf0 * u2.x + xf1 * u2.y + xf2 * u2.z + xf3 * u2.w;
      }
    }
    a0 += b0; a1 += b1; a2 += b2;
    if (qq < 6) {
      sdt[p * 8 + qq] = a0;
      sbc[p * 16 + 2 + qq]  = a1;   // B(qq+2)
      sbc[p * 16 + 10 + qq] = a2;   // C(qq+2)
    } else if (qq == 6) {
      sbc[p * 16 + 0] = a0;         // B0
      sbc[p * 16 + 8] = a1;         // C0
    } else {
      sbc[p * 16 + 1] = a0;         // B1
      sbc[p * 16 + 9] = a1;         // C1
    }
  }
  __syncthreads();

  // --- chunk scan: thread = channel d (192 of 256); delta on the fly ---
  if (tid < 192) {
    const int d = tid;
    float wdt[6];
    #pragma unroll
    for (int r = 0; r < 6; ++r) wdt[r] = W_dt[d * 6 + r];
    const float bdt = b_dt[d];
    const float Dd = D_ssm[d];
    float a[8], h[8], P[8], K[8];
    {
      float4 al0 = *(const float4*)&A_log[d * 8];
      float4 al1 = *(const float4*)&A_log[d * 8 + 4];
      a[0] = -__expf(al0.x); a[1] = -__expf(al0.y); a[2] = -__expf(al0.z); a[3] = -__expf(al0.w);
      a[4] = -__expf(al1.x); a[5] = -__expf(al1.y); a[6] = -__expf(al1.z); a[7] = -__expf(al1.w);
    }
    #pragma unroll
    for (int s = 0; s < 8; ++s) { h[s] = 0.f; P[s] = 1.f; K[s] = 0.f; }
    float ys = 0.f;

    for (int i = 0; i < CLEN; ++i) {
      float xv = (float)sxo[i * 200 + d];
      float sz = (float)szh[i * 198 + d];        // silu(z) precomputed
      float ac = bdt;
      #pragma unroll
      for (int r = 0; r < 6; ++r) ac += sdt[i * 8 + r] * wdt[r];
      float dl = (ac > 20.f) ? ac : log1pf(__expf(ac));   // softplus
      float dx = dl * xv;
      float yl = Dd * xv;
      float4 B0 = *(const float4*)&sbc[i * 16];
      float4 B1 = *(const float4*)&sbc[i * 16 + 4];
      float4 C0 = *(const float4*)&sbc[i * 16 + 8];
      float4 C1 = *(const float4*)&sbc[i * 16 + 12];
      float Bv[8] = {B0.x, B0.y, B0.z, B0.w, B1.x, B1.y, B1.z, B1.w};
      float Cv[8] = {C0.x, C0.y, C0.z, C0.w, C1.x, C1.y, C1.z, C1.w};
      #pragma unroll
      for (int s = 0; s < 8; ++s) {
        float dA = __expf(dl * a[s]);
        h[s] = dA * h[s] + dx * Bv[s];
        yl  += h[s] * Cv[s];
        P[s] *= dA;
        K[s] += P[s] * Cv[s] * sz;
      }
      ys += yl * sz;
    }
    atomicAdd(&ysum[b * 192 + d], ys);
    const int cb = ((b * NCHUNK + c) * 192 + d) * 8;
    *(float4*)&Pc[cb]     = make_float4(P[0], P[1], P[2], P[3]);
    *(float4*)&Pc[cb + 4] = make_float4(P[4], P[5], P[6], P[7]);
    *(float4*)&Qc[cb]     = make_float4(h[0], h[1], h[2], h[3]);
    *(float4*)&Qc[cb + 4] = make_float4(h[4], h[5], h[6], h[7]);
    *(float4*)&Kc[cb]     = make_float4(K[0], K[1], K[2], K[3]);
    *(float4*)&Kc[cb + 4] = make_float4(K[4], K[5], K[6], K[7]);
  }
}

// ---------------------------------------------------------------------------
// Level-1 combine: thread = (b,seg,d,s); 16 serial chunks, coalesced reads.
// ---------------------------------------------------------------------------
__global__ __launch_bounds__(256) void k_comb1(
    const float* __restrict__ Pc, const float* __restrict__ Qc,
    const float* __restrict__ Kc, float* __restrict__ Pg,
    float* __restrict__ Qg, float* __restrict__ Gg, float* __restrict__ Kg)
{
  int t = blockIdx.x * 256 + threadIdx.x;
  int s = t & 7;
  int rr = t >> 3;
  int d = rr % 192;
  int bs = rr / 192;
  int seg = bs & (NSEG - 1);
  int b = bs >> 3;
  float Pp = 1.f, Hl = 0.f, G = 0.f, Kh = 0.f;
  #pragma unroll 4
  for (int ci = 0; ci < SEGC; ++ci) {
    int o = ((b * NCHUNK + seg * SEGC + ci) * 192 + d) * 8 + s;
    float pv = Pc[o], qv = Qc[o], kv = Kc[o];
    G  += kv * Pp;
    Kh += kv * Hl;
    Hl = pv * Hl + qv;
    Pp *= pv;
  }
  Pg[t] = Pp; Qg[t] = Hl; Gg[t] = G; Kg[t] = Kh;
}

// ---------------------------------------------------------------------------
__global__ __launch_bounds__(256) void k_comb2(
    const float* __restrict__ Pg, const float* __restrict__ Qg,
    const float* __restrict__ Gg, const float* __restrict__ Kg,
    float* __restrict__ ysum)
{
  int t = blockIdx.x * 256 + threadIdx.x;
  int s = t & 7;
  int rr = t >> 3;
  int d = rr % 192;
  int b = rr / 192;
  float H = 0.f, acc = 0.f;
  #pragma unroll
  for (int seg = 0; seg < NSEG; ++seg) {
    int o = ((b * NSEG + seg) * 192 + d) * 8 + s;
    acc += Gg[o] * H + Kg[o];
    H = Pg[o] * H + Qg[o];
  }
  acc += __shfl_down(acc, 4);
  acc += __shfl_down(acc, 2);
  acc += __shfl_down(acc, 1);
  if (s == 0) atomicAdd(&ysum[b * 192 + d], acc);
}

// ---------------------------------------------------------------------------
__global__ __launch_bounds__(256) void k_head(
    const float* __restrict__ usum, const float* __restrict__ ysum,
    const float* __restrict__ W_out, const float* __restrict__ fc_w,
    const float* __restrict__ fc_b, const float* __restrict__ mu_w,
    const float* __restrict__ mu_b, const float* __restrict__ sg_w,
    const float* __restrict__ sg_b, float* __restrict__ out)
{
  const int b = blockIdx.x, tid = threadIdx.x;
  __shared__ float e[96];
  __shared__ float tb[256];
  if (tid < 96) {
    const float* wr = W_out + tid * 192;
    const float* yr = ysum + b * 192;
    float acc = usum[b * 96 + tid];
    #pragma unroll 8
    for (int d = 0; d < 192; ++d) acc += yr[d] * wr[d];
    e[tid] = acc * (1.f / (float)LL);
  }
  __syncthreads();
  {
    const float* wr = fc_w + tid * 96;
    float acc = fc_b[tid];
    #pragma unroll 8
    for (int j = 0; j < 96; ++j) acc += e[j] * wr[j];
    float th = tanhf(acc);
    tb[tid] = (th > 0.f) ? th : expm1f(th);
  }
  __syncthreads();
  if (tid < 64) {
    const float* wr = mu_w + tid * 256;
    float acc = mu_b[tid];
    #pragma unroll 8
    for (int i = 0; i < 256; ++i) acc += tb[i] * wr[i];
    out[b * 64 + tid] = acc;
  } else if (tid < 128) {
    int o = tid - 64;
    const float* wr = sg_w + o * 256;
    float acc = sg_b[o];
    #pragma unroll 8
    for (int i = 0; i < 256; ++i) acc += tb[i] * wr[i];
    float el = (acc > 0.f) ? acc : expm1f(acc);
    out[BB * 64 + b * 64 + o] = el + 1.f + 1e-14f;
  }
}

// ---------------------------------------------------------------------------
extern "C" void kernel_launch(void* const* d_in, const int* in_sizes, int n_in,
                              void* d_out, int out_size, void* d_ws, size_t ws_size,
                              hipStream_t stream)
{
  const float* input  = (const float*)d_in[0];
  const float* norm_w = (const float*)d_in[1];
  const float* W_in   = (const float*)d_in[2];
  const float* conv_w = (const float*)d_in[3];
  const float* conv_b = (const float*)d_in[4];
  const float* W_x    = (const float*)d_in[5];
  const float* W_dt   = (const float*)d_in[6];
  const float* b_dt   = (const float*)d_in[7];
  const float* A_log  = (const float*)d_in[8];
  const float* D_ssm  = (const float*)d_in[9];
  const float* W_out  = (const float*)d_in[10];
  const float* fc_w   = (const float*)d_in[11];
  const float* fc_b   = (const float*)d_in[12];
  const float* mu_w   = (const float*)d_in[13];
  const float* mu_b   = (const float*)d_in[14];
  const float* sg_w   = (const float*)d_in[15];
  const float* sg_b   = (const float*)d_in[16];

  float* ws  = (float*)d_ws;
  float* out = (float*)d_out;
  bf16_t* Wbf = (bf16_t*)(ws + WBF_OFF);

  hipMemsetAsync(ws + YSUM_OFF, 0, (BB * 192 + BB * 96) * sizeof(float), stream);

  k_cvt<<<144, 256, 0, stream>>>(W_in, Wbf);
  k_fused<<<BB * NCHUNK, 256, 0, stream>>>(input, norm_w, Wbf, conv_w, conv_b,
      W_x, W_dt, b_dt, A_log, D_ssm,
      ws + P_OFF, ws + Q_OFF, ws + KC_OFF, ws + YSUM_OFF, ws + USUM_OFF);
  k_comb1<<<(BB * NSEG * 192 * 8) / 256, 256, 0, stream>>>(
      ws + P_OFF, ws + Q_OFF, ws + KC_OFF,
      ws + PG_OFF, ws + QG_OFF, ws + GG_OFF, ws + KG_OFF);
  k_comb2<<<(BB * 192 * 8) / 256, 256, 0, stream>>>(
      ws + PG_OFF, ws + QG_OFF, ws + GG_OFF, ws + KG_OFF, ws + YSUM_OFF);
  k_head<<<BB, 256, 0, stream>>>(ws + USUM_OFF, ws + YSUM_OFF, W_out,
      fc_w, fc_b, mu_w, mu_b, sg_w, sg_b, out);
}

// Round 4
// 164.497 us; speedup vs baseline: 2.4781x; 1.4286x over previous
//
#include <hip/hip_runtime.h>
#include <hip/hip_bf16.h>

// Problem constants
#define DM   96
#define DI   192
#define BB   8
#define LL   4096
#define NCHUNK 128
#define CLEN   32
#define NSEG   8
#define SEGC   16

typedef __bf16 bf16_t;
typedef __attribute__((ext_vector_type(8))) __bf16 bf16x8;
typedef __attribute__((ext_vector_type(4))) __bf16 bf16x4;
typedef __attribute__((ext_vector_type(4))) float f32x4;

// Workspace layout (float offsets)
#define P_OFF    0u         // [B,128,192,8]
#define Q_OFF    786432u
#define KC_OFF   1572864u
#define PG_OFF   2359296u   // [B,8,192,8]
#define QG_OFF   2457600u
#define GG_OFF   2555904u
#define KG_OFF   2654208u
#define YSUM_OFF 2752512u   // [B,192]
#define USUM_OFF 2754048u   // [B,96]  (ysum+usum = 2304 floats, zeroed by k_cvt)
#define WBF_OFF  2754816u   // bf16 W_in [384][96]
#define WXB_OFF  2773248u   // bf16 W_x  [32(pad)][192]

// LDS layout (bytes), aggressive aliasing (lifetimes separated by barriers):
//   su  (fp32 34x100=13600) stage->sa-build   | szh (bf16 32x198=12672) MFMA->scan
//   sa  (bf16 48x104= 9984) sa-build->MFMA    | sxo (bf16 32x200=12800) conv->scan
//   sxh (bf16 34x198=13464) MFMA->conv        | sdt(1024)+sbc(2048)     dbc->scan
#define L_SU   0u
#define L_SZH  0u
#define L_SA   13600u
#define L_SXO  13600u
#define L_SXH  26400u
#define L_SDT  26400u
#define L_SBC  27424u
#define L_SSC  39872u    // 34*4=136
#define L_TOT  40016u    // <= 40960 -> 4 blocks/CU, all 1024 blocks resident

// ---------------------------------------------------------------------------
// K0: convert W_in->bf16, W_x->bf16 [32pad][192], zero ysum/usum accumulators.
// ---------------------------------------------------------------------------
__global__ __launch_bounds__(256) void k_cvt(
    const float* __restrict__ W_in, const float* __restrict__ W_x,
    bf16_t* __restrict__ Wbf, bf16_t* __restrict__ Wxb,
    float* __restrict__ acc0)
{
  int i = blockIdx.x * 256 + threadIdx.x;
  if (i < 36864) Wbf[i] = (bf16_t)W_in[i];
  int j = i - 36864;
  if (j >= 0 && j < 6144) Wxb[j] = (j < 22 * 192) ? (bf16_t)W_x[j] : (bf16_t)0.f;
  int k = i - 43008;
  if (k >= 0 && k < 2304) acc0[k] = 0.f;
}

// ---------------------------------------------------------------------------
// Fused: rmsnorm + in-proj MFMA + conv3/silu + dbc MFMA + delta + chunk scan.
// Block = (b, chunk of 32 positions); 256 threads (4 waves).
// ---------------------------------------------------------------------------
__global__ __launch_bounds__(256, 4) void k_fused(
    const float* __restrict__ u, const float* __restrict__ norm_w,
    const bf16_t* __restrict__ Wbf, const bf16_t* __restrict__ Wxb,
    const float* __restrict__ conv_w, const float* __restrict__ conv_b,
    const float* __restrict__ W_dt, const float* __restrict__ b_dt,
    const float* __restrict__ A_log, const float* __restrict__ D_ssm,
    float* __restrict__ Pc, float* __restrict__ Qc, float* __restrict__ Kc,
    float* __restrict__ ysum, float* __restrict__ usum)
{
  __shared__ __align__(16) char lds[L_TOT];
  float*  su  = (float*)(lds + L_SU);
  bf16_t* szh = (bf16_t*)(lds + L_SZH);
  bf16_t* sa  = (bf16_t*)(lds + L_SA);
  bf16_t* sxo = (bf16_t*)(lds + L_SXO);
  bf16_t* sxh = (bf16_t*)(lds + L_SXH);
  float*  sdt = (float*)(lds + L_SDT);
  float*  sbc = (float*)(lds + L_SBC);
  float*  ssc = (float*)(lds + L_SSC);

  const int tid = threadIdx.x;
  const int b   = blockIdx.x >> 7;
  const int c   = blockIdx.x & 127;
  const int wv  = tid >> 6, lane = tid & 63;
  const int q   = lane >> 4, nlo = lane & 15;
  const int l0  = c * CLEN - 2;

  // --- in-proj B fragments (L1/L2-hot after first block) ---
  bf16x8 Bf[6][3];
  #pragma unroll
  for (int nt = 0; nt < 6; ++nt)
    #pragma unroll
    for (int ks = 0; ks < 3; ++ks)
      Bf[nt][ks] = *(const bf16x8*)&Wbf[(wv * 96 + nt * 16 + nlo) * 96 + ks * 32 + q * 8];

  // --- stage u rows l0..l0+33 ---
  for (int i = tid; i < 34 * 24; i += 256) {
    int p = i / 24, k4 = (i - p * 24) * 4;
    int l = l0 + p;
    float4 v = (l >= 0) ? *(const float4*)&u[(b * LL + l) * 96 + k4]
                        : make_float4(0.f, 0.f, 0.f, 0.f);
    *(float4*)&su[p * 100 + k4] = v;
  }
  __syncthreads();

  // --- rms scales + raw-u column sums ---
  if (tid < 34) {
    float s = 0.f;
    #pragma unroll
    for (int k4 = 0; k4 < 24; ++k4) {
      float4 v = *(const float4*)&su[tid * 100 + k4 * 4];
      s += v.x * v.x + v.y * v.y + v.z * v.z + v.w * v.w;
    }
    ssc[tid] = rsqrtf(s * (1.f / 96.f) + 1e-5f);
  } else if (tid >= 64 && tid < 160) {
    int k = tid - 64;
    float s = 0.f;
    #pragma unroll 8
    for (int p = 0; p < 32; ++p) s += su[(p + 2) * 100 + k];
    atomicAdd(&usum[b * 96 + k], s);
  }
  __syncthreads();

  // --- bf16 A tile (scale*norm_w folded), packed 8B stores; zero rows 34..47 ---
  for (int i = tid; i < 34 * 24; i += 256) {
    int p = i / 24, k4 = (i - p * 24) * 4;
    float4 v = *(const float4*)&su[p * 100 + k4];
    float4 nw = *(const float4*)&norm_w[k4];
    float sc = ssc[p];
    bf16x4 o = {(bf16_t)(v.x * sc * nw.x), (bf16_t)(v.y * sc * nw.y),
                (bf16_t)(v.z * sc * nw.z), (bf16_t)(v.w * sc * nw.w)};
    *(bf16x4*)&sa[p * 104 + k4] = o;
  }
  for (int i = tid; i < 14 * 24; i += 256) {
    int p = 34 + i / 24, k4 = (i - (i / 24) * 24) * 4;
    *(bf16x4*)&sa[p * 104 + k4] =
        (bf16x4){(bf16_t)0.f, (bf16_t)0.f, (bf16_t)0.f, (bf16_t)0.f};
  }
  __syncthreads();

  // --- in-proj MFMA; epilogue writes sxh (x half) / szh=silu(z) (overlays su) ---
  #pragma unroll
  for (int mt = 0; mt < 3; ++mt) {
    const int arow = (mt * 16 + nlo) * 104 + q * 8;
    bf16x8 A0 = *(const bf16x8*)&sa[arow];
    bf16x8 A1 = *(const bf16x8*)&sa[arow + 32];
    bf16x8 A2 = *(const bf16x8*)&sa[arow + 64];
    #pragma unroll
    for (int nt = 0; nt < 6; ++nt) {
      f32x4 acc = {0.f, 0.f, 0.f, 0.f};
      acc = __builtin_amdgcn_mfma_f32_16x16x32_bf16(A0, Bf[nt][0], acc, 0, 0, 0);
      acc = __builtin_amdgcn_mfma_f32_16x16x32_bf16(A1, Bf[nt][1], acc, 0, 0, 0);
      acc = __builtin_amdgcn_mfma_f32_16x16x32_bf16(A2, Bf[nt][2], acc, 0, 0, 0);
      int j = wv * 96 + nt * 16 + nlo;
      int row0 = mt * 16 + q * 4;
      if (j < 192) {
        #pragma unroll
        for (int r = 0; r < 4; ++r) {
          int row = row0 + r;
          if (row < 34) sxh[row * 198 + j] = (bf16_t)acc[r];
        }
      } else {
        int jj = j - 192;
        #pragma unroll
        for (int r = 0; r < 4; ++r) {
          int row = row0 + r;
          if (row >= 2 && row < 34) {
            float v = acc[r];
            szh[(row - 2) * 198 + jj] = (bf16_t)(v / (1.f + __expf(-v)));
          }
        }
      }
    }
  }
  __syncthreads();

  // --- prefetch scan constants (latency hidden behind conv/dbc phases) ---
  float wdt[6], bdt = 0.f, Dd = 0.f, a[8];
  if (tid < 192) {
    const int d = tid;
    float2 w01 = *(const float2*)&W_dt[d * 6];
    float2 w23 = *(const float2*)&W_dt[d * 6 + 2];
    float2 w45 = *(const float2*)&W_dt[d * 6 + 4];
    wdt[0] = w01.x; wdt[1] = w01.y; wdt[2] = w23.x;
    wdt[3] = w23.y; wdt[4] = w45.x; wdt[5] = w45.y;
    bdt = b_dt[d];
    Dd = D_ssm[d];
    float4 al0 = *(const float4*)&A_log[d * 8];
    float4 al1 = *(const float4*)&A_log[d * 8 + 4];
    a[0] = -__expf(al0.x); a[1] = -__expf(al0.y); a[2] = -__expf(al0.z); a[3] = -__expf(al0.w);
    a[4] = -__expf(al1.x); a[5] = -__expf(al1.y); a[6] = -__expf(al1.z); a[7] = -__expf(al1.w);
  }

  // --- causal conv3 + SiLU -> sxo (overlays dead sa) ---
  for (int i = tid; i < 32 * 192; i += 256) {
    int p = i / 192, dd = i - p * 192;
    float x0 = (float)sxh[(p + 0) * 198 + dd];
    float x1 = (float)sxh[(p + 1) * 198 + dd];
    float x2 = (float)sxh[(p + 2) * 198 + dd];
    float r = conv_b[dd] + conv_w[dd * 3] * x0 + conv_w[dd * 3 + 1] * x1
            + conv_w[dd * 3 + 2] * x2;
    sxo[p * 200 + dd] = (bf16_t)(r / (1.f + __expf(-r)));
  }
  __syncthreads();

  // --- dbc via MFMA: x'[32x192] @ W_x^T -> sdt/sbc (overlay dead sxh) ---
  {
    const int mt = wv >> 1, nt = wv & 1;
    f32x4 acc = {0.f, 0.f, 0.f, 0.f};
    #pragma unroll
    for (int ks = 0; ks < 6; ++ks) {
      bf16x8 Af  = *(const bf16x8*)&sxo[(mt * 16 + nlo) * 200 + ks * 32 + q * 8];
      bf16x8 Bfx = *(const bf16x8*)&Wxb[(nt * 16 + nlo) * 192 + ks * 32 + q * 8];
      acc = __builtin_amdgcn_mfma_f32_16x16x32_bf16(Af, Bfx, acc, 0, 0, 0);
    }
    int n = nt * 16 + nlo;
    #pragma unroll
    for (int r = 0; r < 4; ++r) {
      int p = mt * 16 + q * 4 + r;
      float v = acc[r];
      if (n < 6)       sdt[p * 8 + n] = v;
      else if (n < 14) sbc[p * 16 + (n - 6)] = v;
      else if (n < 22) sbc[p * 16 + 8 + (n - 14)] = v;
    }
  }
  __syncthreads();

  // --- chunk scan: thread = channel d; delta on the fly ---
  if (tid < 192) {
    const int d = tid;
    float h[8], P[8], K[8];
    #pragma unroll
    for (int s = 0; s < 8; ++s) { h[s] = 0.f; P[s] = 1.f; K[s] = 0.f; }
    float ys = 0.f;

    for (int i = 0; i < CLEN; ++i) {
      float xv = (float)sxo[i * 200 + d];
      float sz = (float)szh[i * 198 + d];
      float ac = bdt;
      #pragma unroll
      for (int r = 0; r < 6; ++r) ac += sdt[i * 8 + r] * wdt[r];
      float dl = (ac > 15.f) ? ac : __logf(1.f + __expf(ac));  // softplus
      float dx = dl * xv;
      float yl = Dd * xv;
      float4 B0 = *(const float4*)&sbc[i * 16];
      float4 B1 = *(const float4*)&sbc[i * 16 + 4];
      float4 C0 = *(const float4*)&sbc[i * 16 + 8];
      float4 C1 = *(const float4*)&sbc[i * 16 + 12];
      float Bv[8] = {B0.x, B0.y, B0.z, B0.w, B1.x, B1.y, B1.z, B1.w};
      float Cv[8] = {C0.x, C0.y, C0.z, C0.w, C1.x, C1.y, C1.z, C1.w};
      #pragma unroll
      for (int s = 0; s < 8; ++s) {
        float dA = __expf(dl * a[s]);
        h[s] = dA * h[s] + dx * Bv[s];
        yl  += h[s] * Cv[s];
        P[s] *= dA;
        K[s] += P[s] * Cv[s] * sz;
      }
      ys += yl * sz;
    }
    atomicAdd(&ysum[b * 192 + d], ys);
    const int cb = ((b * NCHUNK + c) * 192 + d) * 8;
    *(float4*)&Pc[cb]     = make_float4(P[0], P[1], P[2], P[3]);
    *(float4*)&Pc[cb + 4] = make_float4(P[4], P[5], P[6], P[7]);
    *(float4*)&Qc[cb]     = make_float4(h[0], h[1], h[2], h[3]);
    *(float4*)&Qc[cb + 4] = make_float4(h[4], h[5], h[6], h[7]);
    *(float4*)&Kc[cb]     = make_float4(K[0], K[1], K[2], K[3]);
    *(float4*)&Kc[cb + 4] = make_float4(K[4], K[5], K[6], K[7]);
  }
}

// ---------------------------------------------------------------------------
// Level-1 combine: thread = (b,seg,d,s); 16 serial chunks, coalesced reads.
// ---------------------------------------------------------------------------
__global__ __launch_bounds__(256) void k_comb1(
    const float* __restrict__ Pc, const float* __restrict__ Qc,
    const float* __restrict__ Kc, float* __restrict__ Pg,
    float* __restrict__ Qg, float* __restrict__ Gg, float* __restrict__ Kg)
{
  int t = blockIdx.x * 256 + threadIdx.x;
  int s = t & 7;
  int rr = t >> 3;
  int d = rr % 192;
  int bs = rr / 192;
  int seg = bs & (NSEG - 1);
  int b = bs >> 3;
  float Pp = 1.f, Hl = 0.f, G = 0.f, Kh = 0.f;
  #pragma unroll 4
  for (int ci = 0; ci < SEGC; ++ci) {
    int o = ((b * NCHUNK + seg * SEGC + ci) * 192 + d) * 8 + s;
    float pv = Pc[o], qv = Qc[o], kv = Kc[o];
    G  += kv * Pp;
    Kh += kv * Hl;
    Hl = pv * Hl + qv;
    Pp *= pv;
  }
  Pg[t] = Pp; Qg[t] = Hl; Gg[t] = G; Kg[t] = Kh;
}

// ---------------------------------------------------------------------------
// Level-2 combine fused with head. One block per batch.
// ---------------------------------------------------------------------------
__global__ __launch_bounds__(256) void k_head2(
    const float* __restrict__ Pg, const float* __restrict__ Qg,
    const float* __restrict__ Gg, const float* __restrict__ Kg,
    const float* __restrict__ usum, const float* __restrict__ ysum,
    const float* __restrict__ W_out, const float* __restrict__ fc_w,
    const float* __restrict__ fc_b, const float* __restrict__ mu_w,
    const float* __restrict__ mu_b, const float* __restrict__ sg_w,
    const float* __restrict__ sg_b, float* __restrict__ out)
{
  const int b = blockIdx.x, tid = threadIdx.x;
  __shared__ float sy[192];
  __shared__ float e[96];
  __shared__ float tb[256];
  if (tid < 192) sy[tid] = ysum[b * 192 + tid];
  __syncthreads();

  // comb2: 1536 (d,s) chains over 8 segments; 6 chains/thread, coalesced
  #pragma unroll
  for (int ci = 0; ci < 6; ++ci) {
    int cid = ci * 256 + tid;
    int dd = cid >> 3, s = cid & 7;
    float H = 0.f, acc = 0.f;
    #pragma unroll
    for (int seg = 0; seg < NSEG; ++seg) {
      int o = (b * NSEG + seg) * 1536 + cid;
      acc += Gg[o] * H + Kg[o];
      H = Pg[o] * H + Qg[o];
    }
    acc += __shfl_down(acc, 4);
    acc += __shfl_down(acc, 2);
    acc += __shfl_down(acc, 1);
    if (s == 0) atomicAdd(&sy[dd], acc);
  }
  __syncthreads();

  if (tid < 96) {
    const float* wr = W_out + tid * 192;
    float acc = usum[b * 96 + tid];
    #pragma unroll 8
    for (int d = 0; d < 192; ++d) acc += sy[d] * wr[d];
    e[tid] = acc * (1.f / (float)LL);
  }
  __syncthreads();
  {
    const float* wr = fc_w + tid * 96;
    float acc = fc_b[tid];
    #pragma unroll 8
    for (int j = 0; j < 96; ++j) acc += e[j] * wr[j];
    float th = tanhf(acc);
    tb[tid] = (th > 0.f) ? th : expm1f(th);
  }
  __syncthreads();
  if (tid < 64) {
    const float* wr = mu_w + tid * 256;
    float acc = mu_b[tid];
    #pragma unroll 8
    for (int i = 0; i < 256; ++i) acc += tb[i] * wr[i];
    out[b * 64 + tid] = acc;
  } else if (tid < 128) {
    int o = tid - 64;
    const float* wr = sg_w + o * 256;
    float acc = sg_b[o];
    #pragma unroll 8
    for (int i = 0; i < 256; ++i) acc += tb[i] * wr[i];
    float el = (acc > 0.f) ? acc : expm1f(acc);
    out[BB * 64 + b * 64 + o] = el + 1.f + 1e-14f;
  }
}

// ---------------------------------------------------------------------------
extern "C" void kernel_launch(void* const* d_in, const int* in_sizes, int n_in,
                              void* d_out, int out_size, void* d_ws, size_t ws_size,
                              hipStream_t stream)
{
  const float* input  = (const float*)d_in[0];
  const float* norm_w = (const float*)d_in[1];
  const float* W_in   = (const float*)d_in[2];
  const float* conv_w = (const float*)d_in[3];
  const float* conv_b = (const float*)d_in[4];
  const float* W_x    = (const float*)d_in[5];
  const float* W_dt   = (const float*)d_in[6];
  const float* b_dt   = (const float*)d_in[7];
  const float* A_log  = (const float*)d_in[8];
  const float* D_ssm  = (const float*)d_in[9];
  const float* W_out  = (const float*)d_in[10];
  const float* fc_w   = (const float*)d_in[11];
  const float* fc_b   = (const float*)d_in[12];
  const float* mu_w   = (const float*)d_in[13];
  const float* mu_b   = (const float*)d_in[14];
  const float* sg_w   = (const float*)d_in[15];
  const float* sg_b   = (const float*)d_in[16];

  float* ws  = (float*)d_ws;
  float* out = (float*)d_out;
  bf16_t* Wbf = (bf16_t*)(ws + WBF_OFF);
  bf16_t* Wxb = (bf16_t*)(ws + WXB_OFF);

  k_cvt<<<177, 256, 0, stream>>>(W_in, W_x, Wbf, Wxb, ws + YSUM_OFF);
  k_fused<<<BB * NCHUNK, 256, 0, stream>>>(input, norm_w, Wbf, Wxb,
      conv_w, conv_b, W_dt, b_dt, A_log, D_ssm,
      ws + P_OFF, ws + Q_OFF, ws + KC_OFF, ws + YSUM_OFF, ws + USUM_OFF);
  k_comb1<<<(BB * NSEG * 192 * 8) / 256, 256, 0, stream>>>(
      ws + P_OFF, ws + Q_OFF, ws + KC_OFF,
      ws + PG_OFF, ws + QG_OFF, ws + GG_OFF, ws + KG_OFF);
  k_head2<<<BB, 256, 0, stream>>>(
      ws + PG_OFF, ws + QG_OFF, ws + GG_OFF, ws + KG_OFF,
      ws + USUM_OFF, ws + YSUM_OFF, W_out,
      fc_w, fc_b, mu_w, mu_b, sg_w, sg_b, out);
}